// Round 1
// baseline (598.775 us; speedup 1.0000x reference)
//
#include <hip/hip_runtime.h>
#include <hip/hip_bf16.h>

// 2x nearest-neighbor upsample: x[16,128,128,128] f32 -> out[16,128,256,256].
// Each thread: load float2 (2 input cols), store float4 (a,a,b,b) into output
// rows 2h and 2h+1. All loads/stores fully coalesced.
//
// Geometry constants (all powers of two):
//   input row  = 128 floats = 64 float2   -> col2 = tid & 63, row = tid >> 6
//   rows (b*c*h) = 16*128*128 = 262144    -> h = row & 127, bc = row >> 7
//   output row = 256 floats = 64 float4; out rows per (b,c) image = 256

__global__ __launch_bounds__(256) void upsample_57312043598151_kernel(
    const float2* __restrict__ in, float4* __restrict__ out) {
    const int tid = blockIdx.x * blockDim.x + threadIdx.x;  // [0, 16777216)

    const float2 v = in[tid];

    const int col2 = tid & 63;   // which float2 within the input row
    const int r    = tid >> 6;   // flattened (b, c, h) input row index
    const int h    = r & 127;    // input H coordinate
    const int bc   = r >> 7;     // flattened (b, c)

    const int out_row0 = bc * 256 + (h << 1);  // output row index (H_out = 256)

    float4 o;
    o.x = v.x; o.y = v.x; o.z = v.y; o.w = v.y;

    const int idx = out_row0 * 64 + col2;  // float4 index within output
    out[idx]      = o;   // row 2h
    out[idx + 64] = o;   // row 2h+1 (next output row, 64 float4 later)
}

extern "C" void kernel_launch(void* const* d_in, const int* in_sizes, int n_in,
                              void* d_out, int out_size, void* d_ws, size_t ws_size,
                              hipStream_t stream) {
    const float2* in = (const float2*)d_in[0];
    float4* out = (float4*)d_out;

    const int n = in_sizes[0];          // 33,554,432 floats
    const int n_threads = n / 2;        // one thread per float2 = 16,777,216
    const int block = 256;
    const int grid = n_threads / block; // 65,536

    upsample_57312043598151_kernel<<<grid, block, 0, stream>>>(in, out);
}

// Round 3
// 596.856 us; speedup vs baseline: 1.0032x; 1.0032x over previous
//
#include <hip/hip_runtime.h>
#include <hip/hip_bf16.h>

// 2x nearest-neighbor upsample: x[16,128,128,128] f32 -> out[16,128,256,256].
// Each thread: nontemporal-load 2 input cols, nontemporal-store (a,a,b,b)
// into output rows 2h and 2h+1. All accesses coalesced: per wave, load =
// 512 B contiguous, each store = 1 KiB contiguous. NT hints bypass caches
// (512 MiB write stream >> 32 MiB L2 — zero reuse).
//
// Use clang ext_vector types: __builtin_nontemporal_* rejects HIP_vector_type.

typedef float v2f __attribute__((ext_vector_type(2)));
typedef float v4f __attribute__((ext_vector_type(4)));

__global__ __launch_bounds__(256) void upsample_57312043598151_kernel(
    const v2f* __restrict__ in, v4f* __restrict__ out) {
    const int tid = blockIdx.x * blockDim.x + threadIdx.x;  // [0, 16777216)

    const v2f v = __builtin_nontemporal_load(&in[tid]);

    const int col2 = tid & 63;   // float2 index within the input row (W=128 -> 64)
    const int r    = tid >> 6;   // flattened (b, c, h) input row index
    const int h    = r & 127;    // input H coordinate
    const int bc   = r >> 7;     // flattened (b, c)

    const int out_row0 = bc * 256 + (h << 1);  // output row (H_out = 256)

    v4f o;
    o.x = v.x; o.y = v.x; o.z = v.y; o.w = v.y;

    const int idx = out_row0 * 64 + col2;  // float4 index (out row = 64 float4)
    __builtin_nontemporal_store(o, &out[idx]);       // row 2h
    __builtin_nontemporal_store(o, &out[idx + 64]);  // row 2h+1
}

extern "C" void kernel_launch(void* const* d_in, const int* in_sizes, int n_in,
                              void* d_out, int out_size, void* d_ws, size_t ws_size,
                              hipStream_t stream) {
    const v2f* in = (const v2f*)d_in[0];
    v4f* out = (v4f*)d_out;

    const int n = in_sizes[0];          // 33,554,432 floats
    const int n_threads = n / 2;        // one thread per float2 = 16,777,216
    const int block = 256;
    const int grid = n_threads / block; // 65,536

    upsample_57312043598151_kernel<<<grid, block, 0, stream>>>(in, out);
}